// Round 4
// baseline (2165.848 us; speedup 1.0000x reference)
//
#include <hip/hip_runtime.h>
#include <cstdint>
#include <cstddef>

#define BB 4
#define LATN 512
#define NFC 128
#define FIN 384
#define KTOT 131584
#define VV 32768
#define NCALLS 4

typedef unsigned short u16;
typedef unsigned int u32;
typedef __bf16 v8bf __attribute__((ext_vector_type(8)));
typedef float v4f __attribute__((ext_vector_type(4)));

__device__ inline u16 f2bf(float f) {
  u32 u = __builtin_bit_cast(u32, f);
  u += 0x7fffu + ((u >> 16) & 1u);   // RNE
  return (u16)(u >> 16);
}

// ---------------- K1: ks = lat @ W_k + b_k (fp32), wbf = bf16(ks) ----------------
__global__ __launch_bounds__(256) void k_hyper(const float* __restrict__ lat,
    const float* __restrict__ Wk, const float* __restrict__ bk,
    float* __restrict__ ks, u16* __restrict__ wbf)
{
  __shared__ float lats[BB * LATN];
  int tid = threadIdx.x;
  for (int i = tid; i < BB * LATN; i += 256) lats[i] = lat[i];
  __syncthreads();
  int k = blockIdx.x * 256 + tid;          // grid = KTOT/256 = 514
  float a0 = 0.f, a1 = 0.f, a2 = 0.f, a3 = 0.f;
  for (int l = 0; l < LATN; ++l) {
    float w = Wk[(size_t)l * KTOT + k];
    a0 = fmaf(w, lats[l], a0);
    a1 = fmaf(w, lats[LATN + l], a1);
    a2 = fmaf(w, lats[2 * LATN + l], a2);
    a3 = fmaf(w, lats[3 * LATN + l], a3);
  }
  float bv = bk[k];
  a0 += bv; a1 += bv; a2 += bv; a3 += bv;
  ks[k] = a0; ks[KTOT + k] = a1; ks[2 * (size_t)KTOT + k] = a2; ks[3 * (size_t)KTOT + k] = a3;
  wbf[k] = f2bf(a0); wbf[KTOT + k] = f2bf(a1);
  wbf[2 * (size_t)KTOT + k] = f2bf(a2); wbf[3 * (size_t)KTOT + k] = f2bf(a3);
}

// ---------------- K2: out[b,c,:] = inorm(seed[c,:]) for all b ----------------
__global__ __launch_bounds__(256) void k_seednorm(const float* __restrict__ seed,
                                                  float* __restrict__ outb)
{
  int c = blockIdx.x;                      // 128 blocks
  const float* s = seed + (size_t)c * VV;
  int tid = threadIdx.x;
  float sum = 0.f, sq = 0.f;
  for (int v = tid; v < VV; v += 256) { float x = s[v]; sum += x; sq = fmaf(x, x, sq); }
  #pragma unroll
  for (int off = 32; off; off >>= 1) { sum += __shfl_down(sum, off); sq += __shfl_down(sq, off); }
  __shared__ float r0[4], r1[4]; __shared__ float mb, rb;
  int wid = tid >> 6, lid = tid & 63;
  if (lid == 0) { r0[wid] = sum; r1[wid] = sq; }
  __syncthreads();
  if (tid == 0) {
    float st = r0[0] + r0[1] + r0[2] + r0[3];
    float qt = r1[0] + r1[1] + r1[2] + r1[3];
    float m = st / (float)VV;
    float var = qt / (float)VV - m * m;
    mb = m; rb = rsqrtf(var + 1e-5f);
  }
  __syncthreads();
  float m = mb, r = rb;
  for (int v = tid; v < VV; v += 256) {
    float x = (s[v] - m) * r;
    outb[(size_t)(0 * NFC + c) * VV + v] = x;
    outb[(size_t)(1 * NFC + c) * VV + v] = x;
    outb[(size_t)(2 * NFC + c) * VV + v] = x;
    outb[(size_t)(3 * NFC + c) * VV + v] = x;
  }
}

// ---------------- K3: sobel conv + stats, output [k][v] planes (all coalesced) ----
__global__ __launch_bounds__(256) void k_conv(const float* __restrict__ outb,
    u16* __restrict__ yb, float* __restrict__ stats)
{
  int bc = blockIdx.x;                     // b*NFC + c, grid 512
  const float* x = outb + (size_t)bc * VV;
  int b = bc >> 7, c = bc & 127;
  u16* y0 = yb + (size_t)(b * FIN + 3 * c) * VV;
  float s0 = 0, q0 = 0, s1 = 0, q1 = 0, s2 = 0, q2 = 0;
  for (int rr = threadIdx.x; rr < 1024; rr += 256) {
    int d = rr >> 5, h = rr & 31;
    float g1[32], g2[32], g3[32];
    #pragma unroll
    for (int i = 0; i < 32; ++i) { g1[i] = 0.f; g2[i] = 0.f; g3[i] = 0.f; }
    for (int dd = -1; dd <= 1; ++dd) {
      int D = d + dd; if ((unsigned)D >= 32u) continue;
      float fd = (float)dd;
      for (int dh = -1; dh <= 1; ++dh) {
        int H = h + dh; if ((unsigned)H >= 32u) continue;
        float fh = (float)dh;
        const float4* rp = (const float4*)(x + (D << 10) + (H << 5));
        #pragma unroll
        for (int w4 = 0; w4 < 8; ++w4) {
          float4 v = rp[w4];
          int base = w4 * 4;
          g1[base + 0] = fmaf(fd, v.x, g1[base + 0]); g2[base + 0] = fmaf(fh, v.x, g2[base + 0]); g3[base + 0] += v.x;
          g1[base + 1] = fmaf(fd, v.y, g1[base + 1]); g2[base + 1] = fmaf(fh, v.y, g2[base + 1]); g3[base + 1] += v.y;
          g1[base + 2] = fmaf(fd, v.z, g1[base + 2]); g2[base + 2] = fmaf(fh, v.z, g2[base + 2]); g3[base + 2] += v.z;
          g1[base + 3] = fmaf(fd, v.w, g1[base + 3]); g2[base + 3] = fmaf(fh, v.w, g2[base + 3]); g3[base + 3] += v.w;
        }
      }
    }
    int rowoff = rr << 5;
    u16 pa[32], pe[32], pz[32];
    #pragma unroll
    for (int w = 0; w < 32; ++w) {
      float a = g1[w] + (w > 0 ? g1[w - 1] : 0.f) + (w < 31 ? g1[w + 1] : 0.f);
      float e = g2[w] + (w > 0 ? g2[w - 1] : 0.f) + (w < 31 ? g2[w + 1] : 0.f);
      float z = (w < 31 ? g3[w + 1] : 0.f) - (w > 0 ? g3[w - 1] : 0.f);
      s0 += a; q0 = fmaf(a, a, q0);
      s1 += e; q1 = fmaf(e, e, q1);
      s2 += z; q2 = fmaf(z, z, q2);
      pa[w] = f2bf(a); pe[w] = f2bf(e); pz[w] = f2bf(z);
    }
    #pragma unroll
    for (int w8 = 0; w8 < 4; ++w8) {
      *(uint4*)(y0 + rowoff + w8 * 8) = *(uint4*)(pa + w8 * 8);
      *(uint4*)(y0 + (size_t)VV + rowoff + w8 * 8) = *(uint4*)(pe + w8 * 8);
      *(uint4*)(y0 + 2 * (size_t)VV + rowoff + w8 * 8) = *(uint4*)(pz + w8 * 8);
    }
  }
  float vals[6] = { s0, q0, s1, q1, s2, q2 };
  __shared__ float red[6][4];
  int wid = threadIdx.x >> 6, lid = threadIdx.x & 63;
  #pragma unroll
  for (int t = 0; t < 6; ++t) {
    float v = vals[t];
    #pragma unroll
    for (int off = 32; off; off >>= 1) v += __shfl_down(v, off);
    if (lid == 0) red[t][wid] = v;
  }
  __syncthreads();
  if (threadIdx.x == 0) {
    #pragma unroll
    for (int a = 0; a < 3; ++a) {
      float st = red[2 * a][0] + red[2 * a][1] + red[2 * a][2] + red[2 * a][3];
      float qt = red[2 * a + 1][0] + red[2 * a + 1][1] + red[2 * a + 1][2] + red[2 * a + 1][3];
      float m = st / (float)VV;
      float var = qt / (float)VV - m * m;
      float rs = rsqrtf(var + 1e-5f);
      int oc = b * FIN + 3 * c + a;
      stats[2 * oc] = m; stats[2 * oc + 1] = rs;
    }
  }
}

// ---------------- K3b: register transpose yb [b][384][VV] -> yt [b][VV][384] ----
__global__ __launch_bounds__(256) void k_trans(const u16* __restrict__ yb,
                                               u16* __restrict__ yt)
{
  int b = blockIdx.x >> 7;                 // grid 512: 4 b x 128 vtiles
  int vtile = blockIdx.x & 127;
  int tid = threadIdx.x;
  int wave = tid >> 6, lane = tid & 63;
  int vi = lane >> 3, ki = lane & 7;
  int v0 = vtile * 256 + wave * 64 + vi * 8;
  const u16* src = yb + (size_t)b * FIN * VV;
  u16* dst = yt + (size_t)b * VV * FIN;
  union U { uint4 q; u16 s[8]; };
  #pragma unroll
  for (int kb = 0; kb < 6; ++kb) {
    int k0 = kb * 64 + ki * 8;
    U r[8], c[8];
    #pragma unroll
    for (int i = 0; i < 8; ++i)
      r[i].q = *(const uint4*)(src + (size_t)(k0 + i) * VV + v0);
    #pragma unroll
    for (int j = 0; j < 8; ++j) {
      #pragma unroll
      for (int i = 0; i < 8; ++i) c[j].s[i] = r[i].s[j];
    }
    #pragma unroll
    for (int j = 0; j < 8; ++j)
      *(uint4*)(dst + (size_t)(v0 + j) * FIN + k0) = c[j].q;
  }
}

// ---------------- K4: fold norm into w_in / w_sh, adjust biases ----------------
__global__ __launch_bounds__(128) void k_prep(const float* __restrict__ ks,
    const float* __restrict__ stats, u16* __restrict__ wbf, float* __restrict__ badj)
{
  int b = blockIdx.x >> 1, which = blockIdx.x & 1;   // grid 8
  int h = threadIdx.x;
  const float* ksb = ks + (size_t)b * KTOT;
  const float2* st = (const float2*)(stats + b * FIN * 2);
  int woff = which ? 82304 : 0;
  const float* ws = ksb + woff + h * FIN;
  u16* wd = wbf + (size_t)b * KTOT + woff + h * FIN;
  float accm = 0.f;
  for (int cc = 0; cc < FIN; ++cc) {
    float2 mr = st[cc];
    float sw = ws[cc] * mr.y;
    wd[cc] = f2bf(sw);
    accm = fmaf(sw, mr.x, accm);
  }
  int boff = which ? 131456 : 49152;
  badj[b * 256 + which * 128 + h] = ksb[boff + h] - accm;
}

// ---------------- K5: fused MLP, slim-tile version ----------------
// Block 256 thr / 4 waves; block tile N=64 voxels, M=128; wave tile M=128 x N=16.
// acc1+acc3 = 64 AGPR (vs 128 before) -> target 3 waves/SIMD (__launch_bounds 256,3).
// Phase 1 streams yt ONCE feeding w_in (acc1) and w_sh (acc3); B prefetched
// 2 chunks ahead (3-buffer static ring, fully unrolled), w_in A-frags
// rolling-refreshed right after last use. h1/h2 live only in LDS (17.4 KB).
// ph2/3 LDS reads are at the ds_read_b128 bank floor (start banks (ln+q)%8 * 4).
#define HPAD 136

__global__ __launch_bounds__(256, 3) void k_mlp(
    const u16* __restrict__ wbf, const float* __restrict__ ks,
    const float* __restrict__ badj, const u16* __restrict__ yt,
    float* __restrict__ outb)
{
  __shared__ u16 hs[64 * HPAD];            // 17,408 B
  int b = blockIdx.y;
  int tid = threadIdx.x;
  int lane = tid & 63, wave = tid >> 6;
  int ln = lane & 15, quad = lane >> 4;
  int n0 = blockIdx.x * 64;
  int nw = wave * 16;                      // wave's n offset inside tile
  const u16* wb = wbf + (size_t)b * KTOT;
  const float* ksb = ks + (size_t)b * KTOT;
  const float* bj = badj + b * 256;

  // ---- phase 1: acc1 = w_in @ y ; acc3 = w_sh @ y (single yt pass) ----
  v4f acc1[8], acc3[8];
  #pragma unroll
  for (int i = 0; i < 8; ++i) { acc1[i] = (v4f){0,0,0,0}; acc3[i] = (v4f){0,0,0,0}; }

  const u16* x0  = yt + ((size_t)b * VV + n0 + nw + ln) * FIN + quad * 8;
  const u16* api = wb + 0     + (size_t)ln * FIN + quad * 8;
  const u16* aps = wb + 82304 + (size_t)ln * FIN + quad * 8;

  v8bf bufB[3];
  bufB[0] = *(const v8bf*)(x0);
  bufB[1] = *(const v8bf*)(x0 + 32);
  bufB[2] = *(const v8bf*)(x0 + 64);
  v8bf ai[8];
  #pragma unroll
  for (int mt = 0; mt < 8; ++mt) ai[mt] = *(const v8bf*)(api + (size_t)mt * 16 * FIN);

  #pragma unroll
  for (int c = 0; c < 12; ++c) {
    int k0 = c * 32;
    v8bf bv = bufB[c % 3];
    if (c + 3 < 12) bufB[c % 3] = *(const v8bf*)(x0 + k0 + 96);   // 2-deep B prefetch
    #pragma unroll
    for (int mt = 0; mt < 8; ++mt) {
      acc1[mt] = __builtin_amdgcn_mfma_f32_16x16x32_bf16(ai[mt], bv, acc1[mt], 0, 0, 0);
      if (c + 1 < 12)                       // rolling refresh right after last use
        ai[mt] = *(const v8bf*)(api + (size_t)mt * 16 * FIN + k0 + 32);
    }
    #pragma unroll
    for (int mt = 0; mt < 8; ++mt) {
      v8bf as = *(const v8bf*)(aps + (size_t)mt * 16 * FIN + k0);
      acc3[mt] = __builtin_amdgcn_mfma_f32_16x16x32_bf16(as, bv, acc3[mt], 0, 0, 0);
    }
  }

  // epilogue 1: h1 = relu(acc1 + b_in_adj) -> LDS
  #pragma unroll
  for (int mt = 0; mt < 8; ++mt) {
    int m = mt * 16 + quad * 4;
    ushort4 pk;
    pk.x = f2bf(fmaxf(acc1[mt][0] + bj[m + 0], 0.f));
    pk.y = f2bf(fmaxf(acc1[mt][1] + bj[m + 1], 0.f));
    pk.z = f2bf(fmaxf(acc1[mt][2] + bj[m + 2], 0.f));
    pk.w = f2bf(fmaxf(acc1[mt][3] + bj[m + 3], 0.f));
    *(ushort4*)&hs[(nw + ln) * HPAD + m] = pk;
  }
  __syncthreads();

  // ---- phase 2: acc2 = w_mid @ h1 (K=128, B from LDS) ----
  v4f acc2[8];
  #pragma unroll
  for (int i = 0; i < 8; ++i) acc2[i] = (v4f){0,0,0,0};
  const u16* apm = wb + 49280 + (size_t)ln * 128 + quad * 8;
  #pragma unroll
  for (int c = 0; c < 4; ++c) {
    int k0 = c * 32;
    v8bf bv = *(const v8bf*)&hs[(nw + ln) * HPAD + quad * 8 + k0];
    #pragma unroll
    for (int mt = 0; mt < 8; ++mt) {
      v8bf am = *(const v8bf*)(apm + (size_t)mt * 16 * 128 + k0);
      acc2[mt] = __builtin_amdgcn_mfma_f32_16x16x32_bf16(am, bv, acc2[mt], 0, 0, 0);
    }
  }
  __syncthreads();                         // all h1 reads done
  // epilogue 2: h2 = relu(acc2 + b_mid) -> LDS (same buffer)
  #pragma unroll
  for (int mt = 0; mt < 8; ++mt) {
    int m = mt * 16 + quad * 4;
    ushort4 pk;
    pk.x = f2bf(fmaxf(acc2[mt][0] + ksb[65664 + m + 0], 0.f));
    pk.y = f2bf(fmaxf(acc2[mt][1] + ksb[65664 + m + 1], 0.f));
    pk.z = f2bf(fmaxf(acc2[mt][2] + ksb[65664 + m + 2], 0.f));
    pk.w = f2bf(fmaxf(acc2[mt][3] + ksb[65664 + m + 3], 0.f));
    *(ushort4*)&hs[(nw + ln) * HPAD + m] = pk;
  }
  __syncthreads();

  // ---- phase 3: acc3 += w_out @ h2 (K=128, B from LDS) ----
  const u16* apo = wb + 65792 + (size_t)ln * 128 + quad * 8;
  #pragma unroll
  for (int c = 0; c < 4; ++c) {
    int k0 = c * 32;
    v8bf bv = *(const v8bf*)&hs[(nw + ln) * HPAD + quad * 8 + k0];
    #pragma unroll
    for (int mt = 0; mt < 8; ++mt) {
      v8bf ao = *(const v8bf*)(apo + (size_t)mt * 16 * 128 + k0);
      acc3[mt] = __builtin_amdgcn_mfma_f32_16x16x32_bf16(ao, bv, acc3[mt], 0, 0, 0);
    }
  }

  // ---- final epilogue: outb += 0.1*(acc3 + b_out + b_sh_adj) ----
  int n = n0 + nw + ln;
  #pragma unroll
  for (int mt = 0; mt < 8; ++mt) {
    #pragma unroll
    for (int r = 0; r < 4; ++r) {
      int m = mt * 16 + quad * 4 + r;
      float t = acc3[mt][r] + ksb[82176 + m] + bj[128 + m];
      outb[(size_t)(b * 128 + m) * VV + n] += 0.1f * t;
    }
  }
}

// ---------------- K6: channel mean ----------------
__global__ __launch_bounds__(256) void k_mean(const float* __restrict__ outb,
                                              float* __restrict__ dout)
{
  int idx = blockIdx.x * 256 + threadIdx.x;   // 0..131071
  int b = idx >> 15, v = idx & (VV - 1);
  const float* p = outb + (size_t)b * NFC * VV + v;
  float s = 0.f;
  for (int c = 0; c < NFC; ++c) s += p[(size_t)c * VV];
  dout[idx] = s * (1.0f / (float)NFC);
}

extern "C" void kernel_launch(void* const* d_in, const int* in_sizes, int n_in,
                              void* d_out, int out_size, void* d_ws, size_t ws_size,
                              hipStream_t stream)
{
  const float* lat  = (const float*)d_in[0];
  const float* seed = (const float*)d_in[1];
  const float* Wk   = (const float*)d_in[2];
  const float* bk   = (const float*)d_in[3];

  char* p = (char*)d_ws;
  float* ks    = (float*)p; p += (size_t)BB * KTOT * 4;      // 2,105,344
  u16*   wbf   = (u16*)p;   p += (size_t)BB * KTOT * 2;      // 1,052,672
  float* badj  = (float*)p; p += (size_t)BB * 256 * 4;       // 4,096
  float* stats = (float*)p; p += (size_t)BB * FIN * 2 * 4;   // 12,288
  float* outb  = (float*)p; p += (size_t)BB * NFC * VV * 4;  // 67,108,864
  u16*   yb    = (u16*)p;   p += (size_t)BB * FIN * VV * 2;  // 100,663,296  [b][384][v]
  u16*   yt    = (u16*)p;   p += (size_t)BB * VV * FIN * 2;  // 100,663,296  [b][v][384]
  (void)ws_size; (void)in_sizes; (void)n_in; (void)out_size;

  k_hyper<<<dim3(KTOT / 256), 256, 0, stream>>>(lat, Wk, bk, ks, wbf);
  k_seednorm<<<dim3(NFC), 256, 0, stream>>>(seed, outb);

  for (int t = 0; t < NCALLS; ++t) {
    k_conv<<<dim3(BB * NFC), 256, 0, stream>>>(outb, yb, stats);
    k_trans<<<dim3(512), 256, 0, stream>>>(yb, yt);
    k_prep<<<dim3(8), 128, 0, stream>>>(ks, stats, wbf, badj);
    k_mlp<<<dim3(VV / 64, BB), 256, 0, stream>>>(wbf, ks, badj, yt, outb);
  }
  k_mean<<<dim3((BB * VV) / 256), 256, 0, stream>>>(outb, (float*)d_out);
}

// Round 6
// 1605.267 us; speedup vs baseline: 1.3492x; 1.3492x over previous
//
#include <hip/hip_runtime.h>
#include <cstdint>
#include <cstddef>

#define BB 4
#define LATN 512
#define NFC 128
#define FIN 384
#define KTOT 131584
#define VV 32768
#define NCALLS 4

typedef unsigned short u16;
typedef unsigned int u32;
typedef __bf16 v8bf __attribute__((ext_vector_type(8)));
typedef float v4f __attribute__((ext_vector_type(4)));

__device__ inline u16 f2bf(float f) {
  u32 u = __builtin_bit_cast(u32, f);
  u += 0x7fffu + ((u >> 16) & 1u);   // RNE
  return (u16)(u >> 16);
}

// async global->LDS, 16B per lane. lds base MUST be wave-uniform; HW writes
// base + lane*16 (m104/m108 semantics).
__device__ inline void gll16(const u16* g, u16* l) {
  __builtin_amdgcn_global_load_lds(
      (const __attribute__((address_space(1))) u32*)g,
      (__attribute__((address_space(3))) u32*)l, 16, 0, 0);
}

// ---------------- K1: ks = lat @ W_k + b_k (fp32), wbf = bf16(ks) ----------------
__global__ __launch_bounds__(256) void k_hyper(const float* __restrict__ lat,
    const float* __restrict__ Wk, const float* __restrict__ bk,
    float* __restrict__ ks, u16* __restrict__ wbf)
{
  __shared__ float lats[BB * LATN];
  int tid = threadIdx.x;
  for (int i = tid; i < BB * LATN; i += 256) lats[i] = lat[i];
  __syncthreads();
  int k = blockIdx.x * 256 + tid;          // grid = KTOT/256 = 514
  float a0 = 0.f, a1 = 0.f, a2 = 0.f, a3 = 0.f;
  for (int l = 0; l < LATN; ++l) {
    float w = Wk[(size_t)l * KTOT + k];
    a0 = fmaf(w, lats[l], a0);
    a1 = fmaf(w, lats[LATN + l], a1);
    a2 = fmaf(w, lats[2 * LATN + l], a2);
    a3 = fmaf(w, lats[3 * LATN + l], a3);
  }
  float bv = bk[k];
  a0 += bv; a1 += bv; a2 += bv; a3 += bv;
  ks[k] = a0; ks[KTOT + k] = a1; ks[2 * (size_t)KTOT + k] = a2; ks[3 * (size_t)KTOT + k] = a3;
  wbf[k] = f2bf(a0); wbf[KTOT + k] = f2bf(a1);
  wbf[2 * (size_t)KTOT + k] = f2bf(a2); wbf[3 * (size_t)KTOT + k] = f2bf(a3);
}

// ---------------- K2: out[b,c,:] = inorm(seed[c,:]) for all b ----------------
__global__ __launch_bounds__(256) void k_seednorm(const float* __restrict__ seed,
                                                  float* __restrict__ outb)
{
  int c = blockIdx.x;                      // 128 blocks
  const float* s = seed + (size_t)c * VV;
  int tid = threadIdx.x;
  float sum = 0.f, sq = 0.f;
  for (int v = tid; v < VV; v += 256) { float x = s[v]; sum += x; sq = fmaf(x, x, sq); }
  #pragma unroll
  for (int off = 32; off; off >>= 1) { sum += __shfl_down(sum, off); sq += __shfl_down(sq, off); }
  __shared__ float r0[4], r1[4]; __shared__ float mb, rb;
  int wid = tid >> 6, lid = tid & 63;
  if (lid == 0) { r0[wid] = sum; r1[wid] = sq; }
  __syncthreads();
  if (tid == 0) {
    float st = r0[0] + r0[1] + r0[2] + r0[3];
    float qt = r1[0] + r1[1] + r1[2] + r1[3];
    float m = st / (float)VV;
    float var = qt / (float)VV - m * m;
    mb = m; rb = rsqrtf(var + 1e-5f);
  }
  __syncthreads();
  float m = mb, r = rb;
  for (int v = tid; v < VV; v += 256) {
    float x = (s[v] - m) * r;
    outb[(size_t)(0 * NFC + c) * VV + v] = x;
    outb[(size_t)(1 * NFC + c) * VV + v] = x;
    outb[(size_t)(2 * NFC + c) * VV + v] = x;
    outb[(size_t)(3 * NFC + c) * VV + v] = x;
  }
}

// ---------------- K3: sobel conv + stats, output [k][v] planes (all coalesced) ----
__global__ __launch_bounds__(256) void k_conv(const float* __restrict__ outb,
    u16* __restrict__ yb, float* __restrict__ stats)
{
  int bc = blockIdx.x;                     // b*NFC + c, grid 512
  const float* x = outb + (size_t)bc * VV;
  int b = bc >> 7, c = bc & 127;
  u16* y0 = yb + (size_t)(b * FIN + 3 * c) * VV;
  float s0 = 0, q0 = 0, s1 = 0, q1 = 0, s2 = 0, q2 = 0;
  for (int rr = threadIdx.x; rr < 1024; rr += 256) {
    int d = rr >> 5, h = rr & 31;
    float g1[32], g2[32], g3[32];
    #pragma unroll
    for (int i = 0; i < 32; ++i) { g1[i] = 0.f; g2[i] = 0.f; g3[i] = 0.f; }
    for (int dd = -1; dd <= 1; ++dd) {
      int D = d + dd; if ((unsigned)D >= 32u) continue;
      float fd = (float)dd;
      for (int dh = -1; dh <= 1; ++dh) {
        int H = h + dh; if ((unsigned)H >= 32u) continue;
        float fh = (float)dh;
        const float4* rp = (const float4*)(x + (D << 10) + (H << 5));
        #pragma unroll
        for (int w4 = 0; w4 < 8; ++w4) {
          float4 v = rp[w4];
          int base = w4 * 4;
          g1[base + 0] = fmaf(fd, v.x, g1[base + 0]); g2[base + 0] = fmaf(fh, v.x, g2[base + 0]); g3[base + 0] += v.x;
          g1[base + 1] = fmaf(fd, v.y, g1[base + 1]); g2[base + 1] = fmaf(fh, v.y, g2[base + 1]); g3[base + 1] += v.y;
          g1[base + 2] = fmaf(fd, v.z, g1[base + 2]); g2[base + 2] = fmaf(fh, v.z, g2[base + 2]); g3[base + 2] += v.z;
          g1[base + 3] = fmaf(fd, v.w, g1[base + 3]); g2[base + 3] = fmaf(fh, v.w, g2[base + 3]); g3[base + 3] += v.w;
        }
      }
    }
    int rowoff = rr << 5;
    u16 pa[32], pe[32], pz[32];
    #pragma unroll
    for (int w = 0; w < 32; ++w) {
      float a = g1[w] + (w > 0 ? g1[w - 1] : 0.f) + (w < 31 ? g1[w + 1] : 0.f);
      float e = g2[w] + (w > 0 ? g2[w - 1] : 0.f) + (w < 31 ? g2[w + 1] : 0.f);
      float z = (w < 31 ? g3[w + 1] : 0.f) - (w > 0 ? g3[w - 1] : 0.f);
      s0 += a; q0 = fmaf(a, a, q0);
      s1 += e; q1 = fmaf(e, e, q1);
      s2 += z; q2 = fmaf(z, z, q2);
      pa[w] = f2bf(a); pe[w] = f2bf(e); pz[w] = f2bf(z);
    }
    #pragma unroll
    for (int w8 = 0; w8 < 4; ++w8) {
      *(uint4*)(y0 + rowoff + w8 * 8) = *(uint4*)(pa + w8 * 8);
      *(uint4*)(y0 + (size_t)VV + rowoff + w8 * 8) = *(uint4*)(pe + w8 * 8);
      *(uint4*)(y0 + 2 * (size_t)VV + rowoff + w8 * 8) = *(uint4*)(pz + w8 * 8);
    }
  }
  float vals[6] = { s0, q0, s1, q1, s2, q2 };
  __shared__ float red[6][4];
  int wid = threadIdx.x >> 6, lid = threadIdx.x & 63;
  #pragma unroll
  for (int t = 0; t < 6; ++t) {
    float v = vals[t];
    #pragma unroll
    for (int off = 32; off; off >>= 1) v += __shfl_down(v, off);
    if (lid == 0) red[t][wid] = v;
  }
  __syncthreads();
  if (threadIdx.x == 0) {
    #pragma unroll
    for (int a = 0; a < 3; ++a) {
      float st = red[2 * a][0] + red[2 * a][1] + red[2 * a][2] + red[2 * a][3];
      float qt = red[2 * a + 1][0] + red[2 * a + 1][1] + red[2 * a + 1][2] + red[2 * a + 1][3];
      float m = st / (float)VV;
      float var = qt / (float)VV - m * m;
      float rs = rsqrtf(var + 1e-5f);
      int oc = b * FIN + 3 * c + a;
      stats[2 * oc] = m; stats[2 * oc + 1] = rs;
    }
  }
}

// ---------------- K3b: register transpose yb [b][384][VV] -> yt [b][VV][384] ----
__global__ __launch_bounds__(256) void k_trans(const u16* __restrict__ yb,
                                               u16* __restrict__ yt)
{
  int b = blockIdx.x >> 7;                 // grid 512: 4 b x 128 vtiles
  int vtile = blockIdx.x & 127;
  int tid = threadIdx.x;
  int wave = tid >> 6, lane = tid & 63;
  int vi = lane >> 3, ki = lane & 7;
  int v0 = vtile * 256 + wave * 64 + vi * 8;
  const u16* src = yb + (size_t)b * FIN * VV;
  u16* dst = yt + (size_t)b * VV * FIN;
  union U { uint4 q; u16 s[8]; };
  #pragma unroll
  for (int kb = 0; kb < 6; ++kb) {
    int k0 = kb * 64 + ki * 8;
    U r[8], c[8];
    #pragma unroll
    for (int i = 0; i < 8; ++i)
      r[i].q = *(const uint4*)(src + (size_t)(k0 + i) * VV + v0);
    #pragma unroll
    for (int j = 0; j < 8; ++j) {
      #pragma unroll
      for (int i = 0; i < 8; ++i) c[j].s[i] = r[i].s[j];
    }
    #pragma unroll
    for (int j = 0; j < 8; ++j)
      *(uint4*)(dst + (size_t)(v0 + j) * FIN + k0) = c[j].q;
  }
}

// ---------------- K4: fold norm into w_in / w_sh, adjust biases ----------------
__global__ __launch_bounds__(128) void k_prep(const float* __restrict__ ks,
    const float* __restrict__ stats, u16* __restrict__ wbf, float* __restrict__ badj)
{
  int b = blockIdx.x >> 1, which = blockIdx.x & 1;   // grid 8
  int h = threadIdx.x;
  const float* ksb = ks + (size_t)b * KTOT;
  const float2* st = (const float2*)(stats + b * FIN * 2);
  int woff = which ? 82304 : 0;
  const float* ws = ksb + woff + h * FIN;
  u16* wd = wbf + (size_t)b * KTOT + woff + h * FIN;
  float accm = 0.f;
  for (int cc = 0; cc < FIN; ++cc) {
    float2 mr = st[cc];
    float sw = ws[cc] * mr.y;
    wd[cc] = f2bf(sw);
    accm = fmaf(sw, mr.x, accm);
  }
  int boff = which ? 131456 : 49152;
  badj[b * 256 + which * 128 + h] = ksb[boff + h] - accm;
}

// ---------------- K5: fused MLP, LDS-staged weights ----------------
// Round-3 tile (block 256thr/4 waves, N=128, wave M=128 x N=32, acc 128 AGPR) +
// A-operand staging via global_load_lds (zero VGPR, cooperative, 1-chunk-ahead
// dbuf, drained by the per-chunk __syncthreads = m97 structure).
// LDS chunk layout [m 0..127][32 u16] linear. Each wave stages 2x 1KB regions;
// lds base passed wave-uniform (dst + r*512), HW adds lane*16B ->
// dst + r*512 + lane*8 u16 == (m= r*16 + lane/4)*32 + (lane&3)*8 (identity).
// w_sh stays as an 8-reg rolling prefetch; B (yt) is a 2-deep register ring.
#define HPAD 136

__device__ inline void stage_w(const u16* __restrict__ src, int rowstride, int c,
                               u16* dst, int wave, int lane)
{
  #pragma unroll
  for (int i = 0; i < 2; ++i) {
    int r = i * 4 + wave;                  // 8 regions of 1KB
    int m = r * 16 + (lane >> 2);
    int q = lane & 3;
    gll16(src + (size_t)m * rowstride + c * 32 + q * 8,
          dst + r * 512);                  // wave-uniform base; HW adds lane*16B
  }
}

__global__ __launch_bounds__(256, 2) void k_mlp(
    const u16* __restrict__ wbf, const float* __restrict__ ks,
    const float* __restrict__ badj, const u16* __restrict__ yt,
    float* __restrict__ outb)
{
  __shared__ u16 hs[128 * HPAD];           // 34,816 B
  __shared__ u16 AB[2][4096];              // 2 x 8 KB A-chunk double buffer
  int b = blockIdx.y;
  int tid = threadIdx.x;
  int lane = tid & 63, wave = tid >> 6;
  int ln = lane & 15, quad = lane >> 4;
  int n0 = blockIdx.x * 128;
  const u16* wb = wbf + (size_t)b * KTOT;
  const float* ksb = ks + (size_t)b * KTOT;
  const float* bj = badj + b * 256;

  // ---- phase 1: acc1 = w_in @ y ; acc3 = w_sh @ y (single yt pass) ----
  v4f acc1[8][2], acc3[8][2];
  #pragma unroll
  for (int i = 0; i < 8; ++i)
    for (int j = 0; j < 2; ++j) { acc1[i][j] = (v4f){0,0,0,0}; acc3[i][j] = (v4f){0,0,0,0}; }

  stage_w(wb + 0, FIN, 0, AB[0], wave, lane);      // w_in chunk 0 (async)

  const u16* x0  = yt + ((size_t)b * VV + n0 + wave * 32 + ln) * FIN + quad * 8;
  const u16* x1  = x0 + (size_t)16 * FIN;
  const u16* aps = wb + 82304 + (size_t)ln * FIN + quad * 8;
  v8bf as_r[8];
  #pragma unroll
  for (int mt = 0; mt < 8; ++mt) as_r[mt] = *(const v8bf*)(aps + (size_t)mt * 16 * FIN);
  v8bf bA0 = *(const v8bf*)(x0),      bB0 = *(const v8bf*)(x1);
  v8bf bA1 = *(const v8bf*)(x0 + 32), bB1 = *(const v8bf*)(x1 + 32);
  __syncthreads();                                  // chunk 0 staged

  #pragma unroll
  for (int c = 0; c < 12; ++c) {
    if (c + 1 < 12) stage_w(wb + 0, FIN, c + 1, AB[(c + 1) & 1], wave, lane);
    v8bf b0 = (c & 1) ? bA1 : bA0;
    v8bf b1 = (c & 1) ? bB1 : bB0;
    if (c + 2 < 12) {
      if (c & 1) { bA1 = *(const v8bf*)(x0 + (c + 2) * 32); bB1 = *(const v8bf*)(x1 + (c + 2) * 32); }
      else       { bA0 = *(const v8bf*)(x0 + (c + 2) * 32); bB0 = *(const v8bf*)(x1 + (c + 2) * 32); }
    }
    const u16* bufc = AB[c & 1];
    #pragma unroll
    for (int mt = 0; mt < 8; ++mt) {
      v8bf ai = *(const v8bf*)&bufc[(mt * 16 + ln) * 32 + quad * 8];
      acc1[mt][0] = __builtin_amdgcn_mfma_f32_16x16x32_bf16(ai, b0, acc1[mt][0], 0, 0, 0);
      acc1[mt][1] = __builtin_amdgcn_mfma_f32_16x16x32_bf16(ai, b1, acc1[mt][1], 0, 0, 0);
    }
    #pragma unroll
    for (int mt = 0; mt < 8; ++mt) {
      v8bf av = as_r[mt];
      if (c + 1 < 12) as_r[mt] = *(const v8bf*)(aps + (size_t)mt * 16 * FIN + (c + 1) * 32);
      acc3[mt][0] = __builtin_amdgcn_mfma_f32_16x16x32_bf16(av, b0, acc3[mt][0], 0, 0, 0);
      acc3[mt][1] = __builtin_amdgcn_mfma_f32_16x16x32_bf16(av, b1, acc3[mt][1], 0, 0, 0);
    }
    __syncthreads();     // stage(c+1) drained; all reads of AB[c&1] done
  }

  // epilogue 1: h1 = relu(acc1 + b_in_adj) -> LDS
  #pragma unroll
  for (int nt = 0; nt < 2; ++nt) {
    int nl = wave * 32 + nt * 16 + ln;
    #pragma unroll
    for (int mt = 0; mt < 8; ++mt) {
      int m = mt * 16 + quad * 4;
      ushort4 pk;
      pk.x = f2bf(fmaxf(acc1[mt][nt][0] + bj[m + 0], 0.f));
      pk.y = f2bf(fmaxf(acc1[mt][nt][1] + bj[m + 1], 0.f));
      pk.z = f2bf(fmaxf(acc1[mt][nt][2] + bj[m + 2], 0.f));
      pk.w = f2bf(fmaxf(acc1[mt][nt][3] + bj[m + 3], 0.f));
      *(ushort4*)&hs[nl * HPAD + m] = pk;
    }
  }
  stage_w(wb + 49280, 128, 0, AB[0], wave, lane);   // w_mid chunk 0
  __syncthreads();                                  // h1 visible + stage drained

  // ---- phase 2: acc2 = w_mid @ h1 (K=128, A from LDS, B from hs) ----
  v4f acc2[8][2];
  #pragma unroll
  for (int i = 0; i < 8; ++i)
    for (int j = 0; j < 2; ++j) acc2[i][j] = (v4f){0,0,0,0};
  #pragma unroll
  for (int c = 0; c < 4; ++c) {
    if (c + 1 < 4) stage_w(wb + 49280, 128, c + 1, AB[(c + 1) & 1], wave, lane);
    int k0 = c * 32;
    v8bf bv0 = *(const v8bf*)&hs[(wave * 32 + ln) * HPAD + quad * 8 + k0];
    v8bf bv1 = *(const v8bf*)&hs[(wave * 32 + 16 + ln) * HPAD + quad * 8 + k0];
    const u16* bufc = AB[c & 1];
    #pragma unroll
    for (int mt = 0; mt < 8; ++mt) {
      v8bf am = *(const v8bf*)&bufc[(mt * 16 + ln) * 32 + quad * 8];
      acc2[mt][0] = __builtin_amdgcn_mfma_f32_16x16x32_bf16(am, bv0, acc2[mt][0], 0, 0, 0);
      acc2[mt][1] = __builtin_amdgcn_mfma_f32_16x16x32_bf16(am, bv1, acc2[mt][1], 0, 0, 0);
    }
    __syncthreads();
  }

  // epilogue 2: h2 = relu(acc2 + b_mid) -> LDS (same buffer)
  #pragma unroll
  for (int nt = 0; nt < 2; ++nt) {
    int nl = wave * 32 + nt * 16 + ln;
    #pragma unroll
    for (int mt = 0; mt < 8; ++mt) {
      int m = mt * 16 + quad * 4;
      ushort4 pk;
      pk.x = f2bf(fmaxf(acc2[mt][nt][0] + ksb[65664 + m + 0], 0.f));
      pk.y = f2bf(fmaxf(acc2[mt][nt][1] + ksb[65664 + m + 1], 0.f));
      pk.z = f2bf(fmaxf(acc2[mt][nt][2] + ksb[65664 + m + 2], 0.f));
      pk.w = f2bf(fmaxf(acc2[mt][nt][3] + ksb[65664 + m + 3], 0.f));
      *(ushort4*)&hs[nl * HPAD + m] = pk;
    }
  }
  stage_w(wb + 65792, 128, 0, AB[0], wave, lane);   // w_out chunk 0
  __syncthreads();

  // ---- phase 3: acc3 += w_out @ h2 (K=128, A from LDS, B from hs) ----
  #pragma unroll
  for (int c = 0; c < 4; ++c) {
    if (c + 1 < 4) stage_w(wb + 65792, 128, c + 1, AB[(c + 1) & 1], wave, lane);
    int k0 = c * 32;
    v8bf bv0 = *(const v8bf*)&hs[(wave * 32 + ln) * HPAD + quad * 8 + k0];
    v8bf bv1 = *(const v8bf*)&hs[(wave * 32 + 16 + ln) * HPAD + quad * 8 + k0];
    const u16* bufc = AB[c & 1];
    #pragma unroll
    for (int mt = 0; mt < 8; ++mt) {
      v8bf ao = *(const v8bf*)&bufc[(mt * 16 + ln) * 32 + quad * 8];
      acc3[mt][0] = __builtin_amdgcn_mfma_f32_16x16x32_bf16(ao, bv0, acc3[mt][0], 0, 0, 0);
      acc3[mt][1] = __builtin_amdgcn_mfma_f32_16x16x32_bf16(ao, bv1, acc3[mt][1], 0, 0, 0);
    }
    if (c + 1 < 4) __syncthreads();
  }

  // ---- final epilogue: outb += 0.1*(acc3 + b_out + b_sh_adj) ----
  #pragma unroll
  for (int nt = 0; nt < 2; ++nt) {
    int n = n0 + wave * 32 + nt * 16 + ln;
    #pragma unroll
    for (int mt = 0; mt < 8; ++mt) {
      #pragma unroll
      for (int r = 0; r < 4; ++r) {
        int m = mt * 16 + quad * 4 + r;
        float t = acc3[mt][nt][r] + ksb[82176 + m] + bj[128 + m];
        outb[(size_t)(b * 128 + m) * VV + n] += 0.1f * t;
      }
    }
  }
}

// ---------------- K6: channel mean ----------------
__global__ __launch_bounds__(256) void k_mean(const float* __restrict__ outb,
                                              float* __restrict__ dout)
{
  int idx = blockIdx.x * 256 + threadIdx.x;   // 0..131071
  int b = idx >> 15, v = idx & (VV - 1);
  const float* p = outb + (size_t)b * NFC * VV + v;
  float s = 0.f;
  for (int c = 0; c < NFC; ++c) s += p[(size_t)c * VV];
  dout[idx] = s * (1.0f / (float)NFC);
}

extern "C" void kernel_launch(void* const* d_in, const int* in_sizes, int n_in,
                              void* d_out, int out_size, void* d_ws, size_t ws_size,
                              hipStream_t stream)
{
  const float* lat  = (const float*)d_in[0];
  const float* seed = (const float*)d_in[1];
  const float* Wk   = (const float*)d_in[2];
  const float* bk   = (const float*)d_in[3];

  char* p = (char*)d_ws;
  float* ks    = (float*)p; p += (size_t)BB * KTOT * 4;      // 2,105,344
  u16*   wbf   = (u16*)p;   p += (size_t)BB * KTOT * 2;      // 1,052,672
  float* badj  = (float*)p; p += (size_t)BB * 256 * 4;       // 4,096
  float* stats = (float*)p; p += (size_t)BB * FIN * 2 * 4;   // 12,288
  float* outb  = (float*)p; p += (size_t)BB * NFC * VV * 4;  // 67,108,864
  u16*   yb    = (u16*)p;   p += (size_t)BB * FIN * VV * 2;  // 100,663,296  [b][384][v]
  u16*   yt    = (u16*)p;   p += (size_t)BB * VV * FIN * 2;  // 100,663,296  [b][v][384]
  (void)ws_size; (void)in_sizes; (void)n_in; (void)out_size;

  k_hyper<<<dim3(KTOT / 256), 256, 0, stream>>>(lat, Wk, bk, ks, wbf);
  k_seednorm<<<dim3(NFC), 256, 0, stream>>>(seed, outb);

  for (int t = 0; t < NCALLS; ++t) {
    k_conv<<<dim3(BB * NFC), 256, 0, stream>>>(outb, yb, stats);
    k_trans<<<dim3(512), 256, 0, stream>>>(yb, yt);
    k_prep<<<dim3(8), 128, 0, stream>>>(ks, stats, wbf, badj);
    k_mlp<<<dim3(VV / 128, BB), 256, 0, stream>>>(wbf, ks, badj, yt, outb);
  }
  k_mean<<<dim3((BB * VV) / 256), 256, 0, stream>>>(outb, (float*)d_out);
}